// Round 1
// baseline (414.655 us; speedup 1.0000x reference)
//
#include <hip/hip_runtime.h>
#include <cmath>

#define N_NODES 50000
#define N_EDGES 800000
#define D 96

// ---------------- CSR build ----------------

__global__ void k_zero_i32(int* __restrict__ p, int n) {
  int i = blockIdx.x * blockDim.x + threadIdx.x;
  if (i < n) p[i] = 0;
}

__global__ void k_count(const int* __restrict__ dst, int* __restrict__ cnt) {
  int e = blockIdx.x * blockDim.x + threadIdx.x;
  if (e < N_EDGES) atomicAdd(&cnt[dst[e]], 1);
}

__global__ void k_scan1(const int* __restrict__ cnt, int* __restrict__ offs,
                        int* __restrict__ bsum) {
  __shared__ int s[256];
  int i = blockIdx.x * 256 + threadIdx.x;
  int v = (i < N_NODES) ? cnt[i] : 0;
  s[threadIdx.x] = v;
  __syncthreads();
#pragma unroll
  for (int dlt = 1; dlt < 256; dlt <<= 1) {
    int t = (threadIdx.x >= dlt) ? s[threadIdx.x - dlt] : 0;
    __syncthreads();
    s[threadIdx.x] += t;
    __syncthreads();
  }
  if (i < N_NODES) offs[i] = s[threadIdx.x] - v;  // exclusive within block
  if (threadIdx.x == 255) bsum[blockIdx.x] = s[255];
}

__global__ void k_scan2(int* __restrict__ bsum, int nb) {
  __shared__ int s[256];
  int v = (threadIdx.x < nb) ? bsum[threadIdx.x] : 0;
  s[threadIdx.x] = v;
  __syncthreads();
#pragma unroll
  for (int dlt = 1; dlt < 256; dlt <<= 1) {
    int t = (threadIdx.x >= dlt) ? s[threadIdx.x - dlt] : 0;
    __syncthreads();
    s[threadIdx.x] += t;
    __syncthreads();
  }
  if (threadIdx.x < nb) bsum[threadIdx.x] = s[threadIdx.x] - v;  // exclusive
}

__global__ void k_scan3(int* __restrict__ offs, const int* __restrict__ bsum,
                        int* __restrict__ cursor) {
  int i = blockIdx.x * 256 + threadIdx.x;
  if (i < N_NODES) {
    int o = offs[i] + bsum[blockIdx.x];
    offs[i] = o;
    cursor[i] = o;
  }
}

__global__ void k_fill(const int* __restrict__ src, const int* __restrict__ dst,
                       int* __restrict__ cursor, int* __restrict__ ssrc) {
  int e = blockIdx.x * blockDim.x + threadIdx.x;
  if (e < N_EDGES) {
    int p = atomicAdd(&cursor[dst[e]], 1);
    ssrc[p] = src[e];
  }
}

// Build WT[192][96]: WT[k][d] = Wl[d][k] (k<96), Wr[d][k-96] (k>=96)
__global__ void k_buildWT(const float* __restrict__ Wl, const float* __restrict__ Wr,
                          float* __restrict__ WT) {
  int i = blockIdx.x * blockDim.x + threadIdx.x;  // over 192*96
  if (i >= 192 * 96) return;
  int k = i / 96, d = i % 96;
  WT[i] = (k < 96) ? Wl[d * 96 + k] : Wr[d * 96 + (k - 96)];
}

// ---------------- mean aggregation ----------------
// One 32-lane group per node; lane handles d = {lane, lane+32, lane+64}.
// Row reads are 3 fully-coalesced 128B dword loads per neighbor.
__global__ void k_aggregate(const float* __restrict__ xin, const int* __restrict__ offs,
                            const int* __restrict__ cnt, const int* __restrict__ ssrc,
                            float* __restrict__ agg) {
  int sub = threadIdx.x >> 5;
  int lane = threadIdx.x & 31;
  int n = blockIdx.x * 8 + sub;
  if (n >= N_NODES) return;
  int o0 = offs[n];
  int c = cnt[n];
  float a0 = 0.f, a1 = 0.f, a2 = 0.f;
  for (int i = 0; i < c; ++i) {
    int s = ssrc[o0 + i];
    const float* row = xin + (size_t)s * D;
    a0 += row[lane];
    a1 += row[lane + 32];
    a2 += row[lane + 64];
  }
  float inv = 1.0f / fmaxf((float)c, 1.0f);
  float* o = agg + (size_t)n * D;
  o[lane] = a0 * inv;
  o[lane + 32] = a1 * inv;
  o[lane + 64] = a2 * inv;
}

// ---------------- fused linear: out = agg@Wl.T + x@Wr.T + b (+ELU) ----------------
// Block = 384 threads = 4 groups of 96; each group handles 8 nodes.
// Node rows staged in LDS (broadcast float4 reads); WT reads are coalesced.
template <bool ELU>
__global__ void k_linear(const float* __restrict__ agg, const float* __restrict__ xin,
                         const float* __restrict__ WT, const float* __restrict__ bias,
                         float* __restrict__ out) {
  __shared__ float s_a[32 * 96];
  __shared__ float s_x[32 * 96];
  int n0 = blockIdx.x * 32;
  int rem = N_NODES - n0;
  int nval = rem < 32 ? rem : 32;
  int total = nval * 96;
  for (int idx = threadIdx.x; idx < 32 * 96; idx += 384) {
    s_a[idx] = (idx < total) ? agg[(size_t)n0 * 96 + idx] : 0.f;
    s_x[idx] = (idx < total) ? xin[(size_t)n0 * 96 + idx] : 0.f;
  }
  __syncthreads();
  int d = threadIdx.x % 96;
  int g = threadIdx.x / 96;
  float acc[8];
#pragma unroll
  for (int j = 0; j < 8; ++j) acc[j] = 0.f;

  for (int k = 0; k < 96; k += 4) {
    float w0 = WT[(k + 0) * 96 + d];
    float w1 = WT[(k + 1) * 96 + d];
    float w2 = WT[(k + 2) * 96 + d];
    float w3 = WT[(k + 3) * 96 + d];
#pragma unroll
    for (int j = 0; j < 8; ++j) {
      const float4 av = *reinterpret_cast<const float4*>(&s_a[(g * 8 + j) * 96 + k]);
      acc[j] += av.x * w0 + av.y * w1 + av.z * w2 + av.w * w3;
    }
  }
  for (int k = 0; k < 96; k += 4) {
    float w0 = WT[(96 + k + 0) * 96 + d];
    float w1 = WT[(96 + k + 1) * 96 + d];
    float w2 = WT[(96 + k + 2) * 96 + d];
    float w3 = WT[(96 + k + 3) * 96 + d];
#pragma unroll
    for (int j = 0; j < 8; ++j) {
      const float4 xv = *reinterpret_cast<const float4*>(&s_x[(g * 8 + j) * 96 + k]);
      acc[j] += xv.x * w0 + xv.y * w1 + xv.z * w2 + xv.w * w3;
    }
  }

  float bv = bias[d];
#pragma unroll
  for (int j = 0; j < 8; ++j) {
    int n = n0 + g * 8 + j;
    if (n < N_NODES) {
      float v = acc[j] + bv;
      if (ELU) v = (v > 0.f) ? v : expm1f(v);
      out[(size_t)n * 96 + d] = v;
    }
  }
}

// ---------------- launch ----------------

extern "C" void kernel_launch(void* const* d_in, const int* in_sizes, int n_in,
                              void* d_out, int out_size, void* d_ws, size_t ws_size,
                              hipStream_t stream) {
  const float* x = (const float*)d_in[0];
  const int* eidx = (const int*)d_in[1];
  const float* W1l = (const float*)d_in[2];
  const float* b1 = (const float*)d_in[3];
  const float* W1r = (const float*)d_in[4];
  const float* W2l = (const float*)d_in[5];
  const float* b2 = (const float*)d_in[6];
  const float* W2r = (const float*)d_in[7];
  float* out = (float*)d_out;

  const int* src = eidx;
  const int* dst = eidx + N_EDGES;

  char* w = (char*)d_ws;
  auto alloc = [&](size_t bytes) {
    char* p = w;
    w += (bytes + 255) & ~(size_t)255;
    return p;
  };
  int* cnt = (int*)alloc((size_t)N_NODES * 4);
  int* offs = (int*)alloc((size_t)N_NODES * 4);
  int* cursor = (int*)alloc((size_t)N_NODES * 4);
  int* bsum = (int*)alloc(256 * 4);
  int* ssrc = (int*)alloc((size_t)N_EDGES * 4);
  float* WT1 = (float*)alloc(192 * 96 * 4);
  float* WT2 = (float*)alloc(192 * 96 * 4);
  float* agg = (float*)alloc((size_t)N_NODES * 96 * 4);

  const int SB = (N_NODES + 255) / 256;  // 196 scan blocks (<=256)

  k_zero_i32<<<SB, 256, 0, stream>>>(cnt, N_NODES);
  k_count<<<(N_EDGES + 255) / 256, 256, 0, stream>>>(dst, cnt);
  k_scan1<<<SB, 256, 0, stream>>>(cnt, offs, bsum);
  k_scan2<<<1, 256, 0, stream>>>(bsum, SB);
  k_scan3<<<SB, 256, 0, stream>>>(offs, bsum, cursor);
  k_fill<<<(N_EDGES + 255) / 256, 256, 0, stream>>>(src, dst, cursor, ssrc);
  k_buildWT<<<(192 * 96 + 255) / 256, 256, 0, stream>>>(W1l, W1r, WT1);
  k_buildWT<<<(192 * 96 + 255) / 256, 256, 0, stream>>>(W2l, W2r, WT2);

  // layer 1: h1 -> d_out (scratch)
  k_aggregate<<<(N_NODES + 7) / 8, 256, 0, stream>>>(x, offs, cnt, ssrc, agg);
  k_linear<true><<<(N_NODES + 31) / 32, 384, 0, stream>>>(agg, x, WT1, b1, out);
  // layer 2: reads h1 from d_out, writes final to d_out (rows staged in LDS first)
  k_aggregate<<<(N_NODES + 7) / 8, 256, 0, stream>>>(out, offs, cnt, ssrc, agg);
  k_linear<false><<<(N_NODES + 31) / 32, 384, 0, stream>>>(agg, out, WT2, b2, out);
}

// Round 3
// 315.854 us; speedup vs baseline: 1.3128x; 1.3128x over previous
//
#include <hip/hip_runtime.h>
#include <cmath>

#define N_NODES 50000
#define N_EDGES 800000
#define D 96

typedef __bf16 bf16x8 __attribute__((ext_vector_type(8)));
typedef float f32x4 __attribute__((ext_vector_type(4)));

__device__ inline float bflo(unsigned d) { return __uint_as_float(d << 16); }
__device__ inline float bfhi(unsigned d) { return __uint_as_float(d & 0xffff0000u); }
__device__ inline unsigned bfpack(float a, float b) {
  unsigned lo = (unsigned)__builtin_bit_cast(unsigned short, (__bf16)a);
  unsigned hi = (unsigned)__builtin_bit_cast(unsigned short, (__bf16)b);
  return lo | (hi << 16);
}

// ---------------- CSR build ----------------

__global__ void k_zero_i32(int* __restrict__ p, int n) {
  int i = blockIdx.x * blockDim.x + threadIdx.x;
  if (i < n) p[i] = 0;
}

__global__ void k_count(const int* __restrict__ dst, int* __restrict__ cnt) {
  int e = blockIdx.x * blockDim.x + threadIdx.x;
  if (e < N_EDGES) atomicAdd(&cnt[dst[e]], 1);
}

__global__ void k_scan1(const int* __restrict__ cnt, int* __restrict__ offs,
                        int* __restrict__ bsum) {
  __shared__ int s[256];
  int i = blockIdx.x * 256 + threadIdx.x;
  int v = (i < N_NODES) ? cnt[i] : 0;
  s[threadIdx.x] = v;
  __syncthreads();
#pragma unroll
  for (int dlt = 1; dlt < 256; dlt <<= 1) {
    int t = (threadIdx.x >= dlt) ? s[threadIdx.x - dlt] : 0;
    __syncthreads();
    s[threadIdx.x] += t;
    __syncthreads();
  }
  if (i < N_NODES) offs[i] = s[threadIdx.x] - v;
  if (threadIdx.x == 255) bsum[blockIdx.x] = s[255];
}

__global__ void k_scan2(int* __restrict__ bsum, int nb) {
  __shared__ int s[256];
  int v = (threadIdx.x < nb) ? bsum[threadIdx.x] : 0;
  s[threadIdx.x] = v;
  __syncthreads();
#pragma unroll
  for (int dlt = 1; dlt < 256; dlt <<= 1) {
    int t = (threadIdx.x >= dlt) ? s[threadIdx.x - dlt] : 0;
    __syncthreads();
    s[threadIdx.x] += t;
    __syncthreads();
  }
  if (threadIdx.x < nb) bsum[threadIdx.x] = s[threadIdx.x] - v;
}

__global__ void k_scan3(int* __restrict__ offs, const int* __restrict__ bsum,
                        int* __restrict__ cursor) {
  int i = blockIdx.x * 256 + threadIdx.x;
  if (i < N_NODES) {
    int o = offs[i] + bsum[blockIdx.x];
    offs[i] = o;
    cursor[i] = o;
  }
}

__global__ void k_fill(const int* __restrict__ src, const int* __restrict__ dst,
                       int* __restrict__ cursor, int* __restrict__ ssrc) {
  int e = blockIdx.x * blockDim.x + threadIdx.x;
  if (e < N_EDGES) {
    int p = atomicAdd(&cursor[dst[e]], 1);
    ssrc[p] = src[e];
  }
}

// ---------------- f32 -> bf16 conversion (4 elems/thread) ----------------
__global__ void k_tobf16(const float* __restrict__ in, uint2* __restrict__ outd, int n4) {
  int i = blockIdx.x * blockDim.x + threadIdx.x;
  if (i < n4) {
    float4 v = reinterpret_cast<const float4*>(in)[i];
    outd[i] = make_uint2(bfpack(v.x, v.y), bfpack(v.z, v.w));
  }
}

// ---------------- pack WT into MFMA B-fragment layout ----------------
// frag f = t*6+u (t=ktile of 32, u=ntile of 16); lane l, elem j holds
// WT[t*32 + (l>>4)*8 + j][u*16 + (l&15)], WT[k][d] = k<96 ? Wl[d][k] : Wr[d][k-96]
__global__ void k_packW(const float* __restrict__ Wl, const float* __restrict__ Wr,
                        __bf16* __restrict__ Wp) {
  int i = blockIdx.x * blockDim.x + threadIdx.x;  // over 36*512
  if (i >= 36 * 512) return;
  int f = i >> 9, r = i & 511;
  int l = r >> 3, j = r & 7;
  int t = f / 6, u = f % 6;
  int k = t * 32 + (l >> 4) * 8 + j;
  int d = u * 16 + (l & 15);
  float v = (k < 96) ? Wl[d * 96 + k] : Wr[d * 96 + (k - 96)];
  Wp[i] = (__bf16)v;
}

// ---------------- mean aggregation over bf16 rows ----------------
// 32 lanes per node; lane l reads dword l (feats 2l,2l+1), lanes<16 also
// dword 32+l (feats 64+2l, 64+2l+1). Accumulate f32, store bf16.
__global__ void k_aggregate_bf16(const unsigned* __restrict__ xind,
                                 const int* __restrict__ offs,
                                 const int* __restrict__ cnt,
                                 const int* __restrict__ ssrc,
                                 unsigned* __restrict__ aggd) {
  int sub = threadIdx.x >> 5;
  int lane = threadIdx.x & 31;
  int n = blockIdx.x * 8 + sub;
  if (n >= N_NODES) return;
  int o0 = offs[n];
  int c = cnt[n];
  float a0 = 0.f, a1 = 0.f, a2 = 0.f, a3 = 0.f;
  bool half = lane < 16;
  for (int i = 0; i < c; ++i) {
    int s = ssrc[o0 + i];
    const unsigned* row = xind + (size_t)s * 48;
    unsigned d0 = row[lane];
    a0 += bflo(d0);
    a1 += bfhi(d0);
    if (half) {
      unsigned d1 = row[32 + lane];
      a2 += bflo(d1);
      a3 += bfhi(d1);
    }
  }
  float inv = 1.0f / fmaxf((float)c, 1.0f);
  unsigned* o = aggd + (size_t)n * 48;
  o[lane] = bfpack(a0 * inv, a1 * inv);
  if (half) o[32 + lane] = bfpack(a2 * inv, a3 * inv);
}

// ---------------- MFMA linear: out = [A0|A1] @ WT + b (+ELU) ----------------
// Wave handles 16 rows x 96 cols, K=192 (ktiles 0..2 from A0=agg, 3..5 from A1=x).
// All 36 B-frags held in VGPRs; grid-stride over 3125 row-tiles.
template <bool ELU, bool WRITE_BF16>
__global__ void __launch_bounds__(256, 2)
k_linear_mfma(const __bf16* __restrict__ A0, const __bf16* __restrict__ A1,
              const __bf16* __restrict__ Wp, const float* __restrict__ bias,
              float* __restrict__ outf, __bf16* __restrict__ outb) {
  int lane = threadIdx.x & 63;
  int wave = (blockIdx.x * blockDim.x + threadIdx.x) >> 6;
  int nwaves = (gridDim.x * blockDim.x) >> 6;

  bf16x8 B[36];
#pragma unroll
  for (int f = 0; f < 36; ++f)
    B[f] = *reinterpret_cast<const bf16x8*>(Wp + f * 512 + lane * 8);

  int col = lane & 15;
  int rowoff = (lane >> 4) * 4;
  int koff = (lane >> 4) * 8;
  float bv[6];
#pragma unroll
  for (int u = 0; u < 6; ++u) bv[u] = bias[u * 16 + col];

  const int NT = N_NODES / 16;  // 3125
  for (int tile = wave; tile < NT; tile += nwaves) {
    int rowA = tile * 16 + (lane & 15);
    const __bf16* base0 = A0 + (size_t)rowA * 96 + koff;
    const __bf16* base1 = A1 + (size_t)rowA * 96 + koff;
    f32x4 acc[6];
#pragma unroll
    for (int u = 0; u < 6; ++u) acc[u] = (f32x4){0.f, 0.f, 0.f, 0.f};
#pragma unroll
    for (int t = 0; t < 3; ++t) {
      bf16x8 a = *reinterpret_cast<const bf16x8*>(base0 + t * 32);
#pragma unroll
      for (int u = 0; u < 6; ++u)
        acc[u] = __builtin_amdgcn_mfma_f32_16x16x32_bf16(a, B[t * 6 + u], acc[u], 0, 0, 0);
    }
#pragma unroll
    for (int t = 0; t < 3; ++t) {
      bf16x8 a = *reinterpret_cast<const bf16x8*>(base1 + t * 32);
#pragma unroll
      for (int u = 0; u < 6; ++u)
        acc[u] = __builtin_amdgcn_mfma_f32_16x16x32_bf16(a, B[(t + 3) * 6 + u], acc[u], 0, 0, 0);
    }
    // epilogue: D[row=(lane>>4)*4+reg][col=lane&15] per n-tile
#pragma unroll
    for (int u = 0; u < 6; ++u) {
#pragma unroll
      for (int reg = 0; reg < 4; ++reg) {
        int r = tile * 16 + rowoff + reg;
        float v = acc[u][reg] + bv[u];
        if (ELU) v = (v > 0.f) ? v : expm1f(v);
        if (WRITE_BF16)
          outb[(size_t)r * 96 + u * 16 + col] = (__bf16)v;
        else
          outf[(size_t)r * 96 + u * 16 + col] = v;
      }
    }
  }
}

// ---------------- launch ----------------

extern "C" void kernel_launch(void* const* d_in, const int* in_sizes, int n_in,
                              void* d_out, int out_size, void* d_ws, size_t ws_size,
                              hipStream_t stream) {
  const float* x = (const float*)d_in[0];
  const int* eidx = (const int*)d_in[1];
  const float* W1l = (const float*)d_in[2];
  const float* b1 = (const float*)d_in[3];
  const float* W1r = (const float*)d_in[4];
  const float* W2l = (const float*)d_in[5];
  const float* b2 = (const float*)d_in[6];
  const float* W2r = (const float*)d_in[7];
  float* out = (float*)d_out;

  const int* src = eidx;
  const int* dst = eidx + N_EDGES;

  char* w = (char*)d_ws;
  auto alloc = [&](size_t bytes) {
    char* p = w;
    w += (bytes + 255) & ~(size_t)255;
    return p;
  };
  int* cnt = (int*)alloc((size_t)N_NODES * 4);
  int* offs = (int*)alloc((size_t)N_NODES * 4);
  int* cursor = (int*)alloc((size_t)N_NODES * 4);
  int* bsum = (int*)alloc(256 * 4);
  int* ssrc = (int*)alloc((size_t)N_EDGES * 4);
  __bf16* Wp1 = (__bf16*)alloc(36 * 512 * 2);
  __bf16* Wp2 = (__bf16*)alloc(36 * 512 * 2);
  __bf16* xb = (__bf16*)alloc((size_t)N_NODES * 96 * 2);
  __bf16* hb = (__bf16*)alloc((size_t)N_NODES * 96 * 2);
  __bf16* aggb = (__bf16*)alloc((size_t)N_NODES * 96 * 2);

  const int SB = (N_NODES + 255) / 256;

  k_zero_i32<<<SB, 256, 0, stream>>>(cnt, N_NODES);
  k_count<<<(N_EDGES + 255) / 256, 256, 0, stream>>>(dst, cnt);
  k_scan1<<<SB, 256, 0, stream>>>(cnt, offs, bsum);
  k_scan2<<<1, 256, 0, stream>>>(bsum, SB);
  k_scan3<<<SB, 256, 0, stream>>>(offs, bsum, cursor);
  k_fill<<<(N_EDGES + 255) / 256, 256, 0, stream>>>(src, dst, cursor, ssrc);
  k_tobf16<<<(N_NODES * 96 / 4 + 255) / 256, 256, 0, stream>>>(x, (uint2*)xb, N_NODES * 96 / 4);
  k_packW<<<(36 * 512 + 255) / 256, 256, 0, stream>>>(W1l, W1r, Wp1);
  k_packW<<<(36 * 512 + 255) / 256, 256, 0, stream>>>(W2l, W2r, Wp2);

  // layer 1
  k_aggregate_bf16<<<(N_NODES + 7) / 8, 256, 0, stream>>>(
      (const unsigned*)xb, offs, cnt, ssrc, (unsigned*)aggb);
  k_linear_mfma<true, true><<<200, 256, 0, stream>>>(aggb, xb, Wp1, b1, nullptr, hb);
  // layer 2
  k_aggregate_bf16<<<(N_NODES + 7) / 8, 256, 0, stream>>>(
      (const unsigned*)hb, offs, cnt, ssrc, (unsigned*)aggb);
  k_linear_mfma<false, false><<<200, 256, 0, stream>>>(aggb, hb, Wp2, b2, out, nullptr);
}

// Round 4
// 259.436 us; speedup vs baseline: 1.5983x; 1.2175x over previous
//
#include <hip/hip_runtime.h>
#include <cmath>

#define N_NODES 50000
#define N_EDGES 800000
#define D 96

#define NB 500            // dst buckets
#define BN 100            // nodes per bucket (NB*BN == N_NODES)
#define BN2 128           // padded local-scan width
#define G 128             // scatter chunks
#define CHUNK ((N_EDGES + G - 1) / G)  // 6250
#define PADQ 16           // pad (chunk,bucket) segments to 16 entries (64B)
#define CAP 4096          // LDS sorted capacity per pass

typedef __bf16 bf16x8 __attribute__((ext_vector_type(8)));
typedef float f32x4 __attribute__((ext_vector_type(4)));

__device__ inline float bflo(unsigned d) { return __uint_as_float(d << 16); }
__device__ inline float bfhi(unsigned d) { return __uint_as_float(d & 0xffff0000u); }
__device__ inline unsigned bfpack(float a, float b) {
  unsigned lo = (unsigned)__builtin_bit_cast(unsigned short, (__bf16)a);
  unsigned hi = (unsigned)__builtin_bit_cast(unsigned short, (__bf16)b);
  return lo | (hi << 16);
}

// ---------------- bucket partition ----------------
// hist[b*G+g] = padded count of chunk-g edges with dst in bucket b
__global__ void k_hist(const int* __restrict__ dst, int* __restrict__ hist) {
  __shared__ int h[NB];
  int tid = threadIdx.x, g = blockIdx.x;
  for (int i = tid; i < NB; i += 256) h[i] = 0;
  __syncthreads();
  int e0 = g * CHUNK, e1 = min(e0 + CHUNK, N_EDGES);
  for (int e = e0 + tid; e < e1; e += 256) atomicAdd(&h[dst[e] / BN], 1);
  __syncthreads();
  for (int b = tid; b < NB; b += 256)
    hist[b * G + g] = (h[b] + PADQ - 1) & ~(PADQ - 1);
}

// per-bucket exclusive scan over chunks; btot[b] = padded bucket total
__global__ void k_chunkscan(const int* __restrict__ hist, int* __restrict__ chunkoff,
                            int* __restrict__ btot) {
  __shared__ int s[G];
  int b = blockIdx.x, g = threadIdx.x;
  int v = hist[b * G + g];
  s[g] = v;
  __syncthreads();
#pragma unroll
  for (int d = 1; d < G; d <<= 1) {
    int t = (g >= d) ? s[g - d] : 0;
    __syncthreads();
    s[g] += t;
    __syncthreads();
  }
  chunkoff[b * G + g] = s[g] - v;
  if (g == G - 1) btot[b] = s[g];
}

// exclusive scan over buckets
__global__ void k_bscan(const int* __restrict__ btot, int* __restrict__ boffs) {
  __shared__ int s[512];
  int i = threadIdx.x;
  int v = (i < NB) ? btot[i] : 0;
  s[i] = v;
  __syncthreads();
#pragma unroll
  for (int d = 1; d < 512; d <<= 1) {
    int t = (i >= d) ? s[i - d] : 0;
    __syncthreads();
    s[i] += t;
    __syncthreads();
  }
  if (i < NB) boffs[i] = s[i] - v;
}

// scatter packed entries src(16b)|dloc<<16 into private padded segments
__global__ void k_scatter(const int* __restrict__ src, const int* __restrict__ dst,
                          const int* __restrict__ hist, const int* __restrict__ chunkoff,
                          const int* __restrict__ boffs, unsigned* __restrict__ pairs) {
  __shared__ int cbase[NB], cur[NB], pcnt[NB];
  int tid = threadIdx.x, g = blockIdx.x;
  for (int b = tid; b < NB; b += 512) {
    int cb = boffs[b] + chunkoff[b * G + g];
    cbase[b] = cb;
    cur[b] = cb;
    pcnt[b] = hist[b * G + g];
  }
  __syncthreads();
  int e0 = g * CHUNK, e1 = min(e0 + CHUNK, N_EDGES);
  for (int e = e0 + tid; e < e1; e += 512) {
    int d = dst[e];
    int b = d / BN;
    int p = atomicAdd(&cur[b], 1);
    pairs[p] = (unsigned)src[e] | ((unsigned)(d - b * BN) << 16);
  }
  __syncthreads();
  // fill pad slots with sentinel dloc=127 (never aggregated)
  for (int b = tid; b < NB; b += 512) {
    int end = cbase[b] + pcnt[b];
    for (int p = cur[b]; p < end; ++p) pairs[p] = (127u << 16);
  }
}

// ---------------- f32 -> bf16 conversion ----------------
__global__ void k_tobf16(const float* __restrict__ in, uint2* __restrict__ outd, int n4) {
  int i = blockIdx.x * blockDim.x + threadIdx.x;
  if (i < n4) {
    float4 v = reinterpret_cast<const float4*>(in)[i];
    outd[i] = make_uint2(bfpack(v.x, v.y), bfpack(v.z, v.w));
  }
}

// ---------------- pack WT into MFMA B-fragment layout ----------------
__global__ void k_packW(const float* __restrict__ Wl, const float* __restrict__ Wr,
                        __bf16* __restrict__ Wp) {
  int i = blockIdx.x * blockDim.x + threadIdx.x;
  if (i >= 36 * 512) return;
  int f = i >> 9, r = i & 511;
  int l = r >> 3, j = r & 7;
  int t = f / 6, u = f % 6;
  int k = t * 32 + (l >> 4) * 8 + j;
  int d = u * 16 + (l & 15);
  float v = (k < 96) ? Wl[d * 96 + k] : Wr[d * 96 + (k - 96)];
  Wp[i] = (__bf16)v;
}

// ---------------- fused LDS-sort + mean aggregation ----------------
// Block b handles bucket b (nodes b*100..b*100+99). Sorts its edges by local
// node in LDS, then 32-lane clusters aggregate nodes round-robin.
__global__ void __launch_bounds__(512)
k_agg_fused(const unsigned* __restrict__ xind, const unsigned* __restrict__ pairs,
            const int* __restrict__ boffs, const int* __restrict__ btot,
            unsigned* __restrict__ aggd) {
  __shared__ int sorted[CAP];
  __shared__ int h[BN2], seg[BN2], cur[BN2];
  int tid = threadIdx.x;
  int b = blockIdx.x;
  int c = tid >> 5, lane = tid & 31;
  bool half = lane < 16;
  int ebase = boffs[b];
  int ecnt = btot[b];

  float a0[7], a1[7], a2[7], a3[7];
  int ctot[7];
#pragma unroll
  for (int t = 0; t < 7; ++t) {
    a0[t] = a1[t] = a2[t] = a3[t] = 0.f;
    ctot[t] = 0;
  }

  for (int p0 = 0; p0 < ecnt; p0 += CAP) {
    int pcnt = min(CAP, ecnt - p0);
    for (int i = tid; i < BN2; i += 512) h[i] = 0;
    __syncthreads();
    for (int i = tid; i < pcnt; i += 512) {
      unsigned pr = pairs[ebase + p0 + i];
      atomicAdd(&h[(pr >> 16) & 127], 1);
    }
    __syncthreads();
    // inclusive scan of h over 128 (threads < 128 participate)
    {
      int v = 0;
      if (tid < BN2) {
        v = h[tid];
        seg[tid] = v;
      }
      __syncthreads();
#pragma unroll
      for (int d = 1; d < BN2; d <<= 1) {
        int t = 0;
        if (tid < BN2 && tid >= d) t = seg[tid - d];
        __syncthreads();
        if (tid < BN2) seg[tid] += t;
        __syncthreads();
      }
      if (tid < BN2) {
        int e = seg[tid] - v;  // exclusive
        seg[tid] = e;
        cur[tid] = e;
      }
      __syncthreads();
    }
    for (int i = tid; i < pcnt; i += 512) {
      unsigned pr = pairs[ebase + p0 + i];
      int q = atomicAdd(&cur[(pr >> 16) & 127], 1);
      sorted[q] = (int)(pr & 0xffffu);
    }
    __syncthreads();
    // aggregate: cluster c handles local nodes c, c+16, ...
#pragma unroll
    for (int t = 0; t < 7; ++t) {
      int j = c + 16 * t;
      if (j < BN) {
        int st = seg[j], cn = h[j];
        for (int i = 0; i < cn; ++i) {
          int s = sorted[st + i];
          const unsigned* row = xind + (size_t)s * 48;
          unsigned d0 = row[lane];
          a0[t] += bflo(d0);
          a1[t] += bfhi(d0);
          if (half) {
            unsigned d1 = row[32 + lane];
            a2[t] += bflo(d1);
            a3[t] += bfhi(d1);
          }
        }
        ctot[t] += cn;
      }
    }
    __syncthreads();
  }
  // write means
#pragma unroll
  for (int t = 0; t < 7; ++t) {
    int j = c + 16 * t;
    if (j < BN) {
      int n = b * BN + j;
      float inv = 1.0f / fmaxf((float)ctot[t], 1.0f);
      unsigned* o = aggd + (size_t)n * 48;
      o[lane] = bfpack(a0[t] * inv, a1[t] * inv);
      if (half) o[32 + lane] = bfpack(a2[t] * inv, a3[t] * inv);
    }
  }
}

// ---------------- MFMA linear: out = [A0|A1] @ WT + b (+ELU) ----------------
template <bool ELU, bool WRITE_BF16>
__global__ void __launch_bounds__(256, 2)
k_linear_mfma(const __bf16* __restrict__ A0, const __bf16* __restrict__ A1,
              const __bf16* __restrict__ Wp, const float* __restrict__ bias,
              float* __restrict__ outf, __bf16* __restrict__ outb) {
  int lane = threadIdx.x & 63;
  int wave = (blockIdx.x * blockDim.x + threadIdx.x) >> 6;
  int nwaves = (gridDim.x * blockDim.x) >> 6;

  bf16x8 B[36];
#pragma unroll
  for (int f = 0; f < 36; ++f)
    B[f] = *reinterpret_cast<const bf16x8*>(Wp + f * 512 + lane * 8);

  int col = lane & 15;
  int rowoff = (lane >> 4) * 4;
  int koff = (lane >> 4) * 8;
  float bv[6];
#pragma unroll
  for (int u = 0; u < 6; ++u) bv[u] = bias[u * 16 + col];

  const int NT = N_NODES / 16;  // 3125
  for (int tile = wave; tile < NT; tile += nwaves) {
    int rowA = tile * 16 + (lane & 15);
    const __bf16* base0 = A0 + (size_t)rowA * 96 + koff;
    const __bf16* base1 = A1 + (size_t)rowA * 96 + koff;
    f32x4 acc[6];
#pragma unroll
    for (int u = 0; u < 6; ++u) acc[u] = (f32x4){0.f, 0.f, 0.f, 0.f};
#pragma unroll
    for (int t = 0; t < 3; ++t) {
      bf16x8 a = *reinterpret_cast<const bf16x8*>(base0 + t * 32);
#pragma unroll
      for (int u = 0; u < 6; ++u)
        acc[u] = __builtin_amdgcn_mfma_f32_16x16x32_bf16(a, B[t * 6 + u], acc[u], 0, 0, 0);
    }
#pragma unroll
    for (int t = 0; t < 3; ++t) {
      bf16x8 a = *reinterpret_cast<const bf16x8*>(base1 + t * 32);
#pragma unroll
      for (int u = 0; u < 6; ++u)
        acc[u] = __builtin_amdgcn_mfma_f32_16x16x32_bf16(a, B[(t + 3) * 6 + u], acc[u], 0, 0, 0);
    }
#pragma unroll
    for (int u = 0; u < 6; ++u) {
#pragma unroll
      for (int reg = 0; reg < 4; ++reg) {
        int r = tile * 16 + rowoff + reg;
        float v = acc[u][reg] + bv[u];
        if (ELU) v = (v > 0.f) ? v : expm1f(v);
        if (WRITE_BF16)
          outb[(size_t)r * 96 + u * 16 + col] = (__bf16)v;
        else
          outf[(size_t)r * 96 + u * 16 + col] = v;
      }
    }
  }
}

// ---------------- launch ----------------

extern "C" void kernel_launch(void* const* d_in, const int* in_sizes, int n_in,
                              void* d_out, int out_size, void* d_ws, size_t ws_size,
                              hipStream_t stream) {
  const float* x = (const float*)d_in[0];
  const int* eidx = (const int*)d_in[1];
  const float* W1l = (const float*)d_in[2];
  const float* b1 = (const float*)d_in[3];
  const float* W1r = (const float*)d_in[4];
  const float* W2l = (const float*)d_in[5];
  const float* b2 = (const float*)d_in[6];
  const float* W2r = (const float*)d_in[7];
  float* out = (float*)d_out;

  const int* src = eidx;
  const int* dst = eidx + N_EDGES;

  char* w = (char*)d_ws;
  auto alloc = [&](size_t bytes) {
    char* p = w;
    w += (bytes + 255) & ~(size_t)255;
    return p;
  };
  int* hist = (int*)alloc((size_t)NB * G * 4);
  int* chunkoff = (int*)alloc((size_t)NB * G * 4);
  int* btot = (int*)alloc(NB * 4);
  int* boffs = (int*)alloc(NB * 4);
  unsigned* pairs = (unsigned*)alloc(((size_t)N_EDGES + (size_t)NB * G * (PADQ - 1)) * 4);
  __bf16* Wp1 = (__bf16*)alloc(36 * 512 * 2);
  __bf16* Wp2 = (__bf16*)alloc(36 * 512 * 2);
  __bf16* xb = (__bf16*)alloc((size_t)N_NODES * 96 * 2);
  __bf16* hb = (__bf16*)alloc((size_t)N_NODES * 96 * 2);
  __bf16* aggb = (__bf16*)alloc((size_t)N_NODES * 96 * 2);

  // bucket partition (once; reused by both layers)
  k_hist<<<G, 256, 0, stream>>>(dst, hist);
  k_chunkscan<<<NB, G, 0, stream>>>(hist, chunkoff, btot);
  k_bscan<<<1, 512, 0, stream>>>(btot, boffs);
  k_scatter<<<G, 512, 0, stream>>>(src, dst, hist, chunkoff, boffs, pairs);

  k_tobf16<<<(N_NODES * 96 / 4 + 255) / 256, 256, 0, stream>>>(x, (uint2*)xb, N_NODES * 96 / 4);
  k_packW<<<(36 * 512 + 255) / 256, 256, 0, stream>>>(W1l, W1r, Wp1);
  k_packW<<<(36 * 512 + 255) / 256, 256, 0, stream>>>(W2l, W2r, Wp2);

  // layer 1
  k_agg_fused<<<NB, 512, 0, stream>>>((const unsigned*)xb, pairs, boffs, btot, (unsigned*)aggb);
  k_linear_mfma<true, true><<<200, 256, 0, stream>>>(aggb, xb, Wp1, b1, nullptr, hb);
  // layer 2
  k_agg_fused<<<NB, 512, 0, stream>>>((const unsigned*)hb, pairs, boffs, btot, (unsigned*)aggb);
  k_linear_mfma<false, false><<<200, 256, 0, stream>>>(aggb, hb, Wp2, b2, out, nullptr);
}